// Round 1
// baseline (33.855 us; speedup 1.0000x reference)
//
#include <hip/hip_runtime.h>
#include <math.h>

// ---------------- constants (atomic units) ----------------
constexpr double B2A   = 0.52917721067;
constexpr double H2KJ  = 2625.499638;
constexpr double RCUT  = 10.0 / B2A;
constexpr double RCUT2 = RCUT * RCUT;

constexpr double Zc_[2]   = {3.61565, 0.93619};
constexpr double MONO_[2] = {-0.390896, 0.195448};
constexpr double QSH_[2]  = {MONO_[0] - Zc_[0], MONO_[1] - Zc_[1]};
constexpr double DIPO_[2][3] = {{0.0, 0.0, -0.094298},
                                {0.0910288, 0.0, -0.207851}};
constexpr double QS_[2][5] = {{-0.330685, 0.0, 0.0, 0.869923, 0.0},
                              {-0.0739388, 0.0929482, 0.0, 0.00532425, 0.0}};
constexpr double B_EL_[2]  = {2.13358, 2.33322};
constexpr double B_PA_[2]  = {2.1975, 1.96474};
constexpr double KM_PA_[2] = {6.50923 / QSH_[0], 0.527804 / QSH_[1]};
constexpr double KD_PA_[2] = {-5.61925, -0.515584};
constexpr double KQ_PA_[2] = {-1.56567, -0.440164};
constexpr double C6_[2]    = {35.8289, 1.98954};
constexpr double B_D_[2]   = {1.84302, 1.30993};
constexpr double AD_[2][3] = {{4.45992, 6.07259, 4.55391},
                              {2.22001, 1.66835, 0.183855}};
constexpr double ETA_[2]   = {6.18699e-06 * 2.0, 0.561535 * 2.0};
constexpr double B_XP_[2]  = {2.73582, 2.04028};
constexpr double KM_XP_[2] = {1.26592 / QSH_[0], 0.200089 / QSH_[1]};
constexpr double B_CT_[2]  = {1.89485, 2.36763};
constexpr double KM_AC_[2] = {-0.67857 / QSH_[0], 1.36735 / QSH_[1]};
constexpr double KM_DO_[2] = {0.757752 / QSH_[0], 0.00888982 / QSH_[1]};
constexpr double KD_DO_[2] = {-0.512036, -0.0511668};
constexpr double KQ_DO_[2] = {-0.208186, 0.0568152};
constexpr double EPS_OFF = 0.380979;
constexpr double EPS_ON  = 1.0e15;

constexpr double D_M   = 524.265 / H2KJ;
constexpr double K_B   = 5098.15 / H2KJ * B2A * B2A;
constexpr double B_EQ  = 0.958413 / B2A;
constexpr double K_BB  = -61.1423 / H2KJ * B2A * B2A;
constexpr double K_BA  = -159.886 / H2KJ * B2A;
constexpr double TH_EQ = 104.4234 * M_PI / 180.0;
constexpr double K_TH  = 452.183 / H2KJ;
constexpr double SQ32  = 0.86602540378443864676;  // sqrt(3)/2

// ws layout (doubles): mu[N*3] | Qm[N*9] | alpha[N*9] | Efld[N*3] | dq[N] | epart[N]
#define WS_MU(ws, N)    ((ws))
#define WS_QM(ws, N)    ((ws) + 3 * (N))
#define WS_AL(ws, N)    ((ws) + 12 * (N))
#define WS_EF(ws, N)    ((ws) + 21 * (N))
#define WS_DQ(ws, N)    ((ws) + 24 * (N))
#define WS_EP(ws, N)    ((ws) + 25 * (N))

struct d3 { double x, y, z; };
__device__ inline d3 operator-(d3 a, d3 b) { return {a.x - b.x, a.y - b.y, a.z - b.z}; }
__device__ inline d3 operator+(d3 a, d3 b) { return {a.x + b.x, a.y + b.y, a.z + b.z}; }
__device__ inline d3 operator*(d3 a, double s) { return {a.x * s, a.y * s, a.z * s}; }
__device__ inline double dotd(d3 a, d3 b) { return a.x * b.x + a.y * b.y + a.z * b.z; }
__device__ inline d3 crossd(d3 a, d3 b) {
    return {a.y * b.z - a.z * b.y, a.z * b.x - a.x * b.z, a.x * b.y - a.y * b.x};
}
__device__ inline d3 normd(d3 a) {
    double s = 1.0 / sqrt(dotd(a, a));
    return a * s;
}

__device__ inline void load_box(const float* box, double bx[3][3], double bi[3][3]) {
    for (int i = 0; i < 3; ++i)
        for (int j = 0; j < 3; ++j) bx[i][j] = (double)box[i * 3 + j];
    double a = bx[0][0], b = bx[0][1], c = bx[0][2];
    double d = bx[1][0], e = bx[1][1], f = bx[1][2];
    double g = bx[2][0], h = bx[2][1], i2 = bx[2][2];
    double A =  (e * i2 - f * h), B = -(d * i2 - f * g), C =  (d * h - e * g);
    double D = -(b * i2 - c * h), E =  (a * i2 - c * g), F = -(a * h - b * g);
    double G =  (b * f - c * e),  H = -(a * f - c * d),  I =  (a * e - b * d);
    double det = a * A + b * B + c * C;
    double s = 1.0 / det;
    bi[0][0] = A * s; bi[0][1] = D * s; bi[0][2] = G * s;
    bi[1][0] = B * s; bi[1][1] = E * s; bi[1][2] = H * s;
    bi[2][0] = C * s; bi[2][1] = F * s; bi[2][2] = I * s;
}

__device__ inline d3 pbc(d3 d, const double bx[3][3], const double bi[3][3]) {
    double s0 = d.x * bi[0][0] + d.y * bi[1][0] + d.z * bi[2][0];
    double s1 = d.x * bi[0][1] + d.y * bi[1][1] + d.z * bi[2][1];
    double s2 = d.x * bi[0][2] + d.y * bi[1][2] + d.z * bi[2][2];
    s0 = rint(s0); s1 = rint(s1); s2 = rint(s2);  // jnp.round = ties-to-even
    d.x -= s0 * bx[0][0] + s1 * bx[1][0] + s2 * bx[2][0];
    d.y -= s0 * bx[0][1] + s1 * bx[1][1] + s2 * bx[2][1];
    d.z -= s0 * bx[0][2] + s1 * bx[1][2] + s2 * bx[2][2];
    return d;
}

__device__ inline d3 getc(const float* coords, int i) {
    return {(double)coords[3 * i], (double)coords[3 * i + 1], (double)coords[3 * i + 2]};
}

__device__ inline double f1damp(double u) { return 1.0 - exp(-u) * (1.0 + 0.5 * u); }

// -------------------- kernel 1: frames + rotated multipoles --------------------
__global__ void k_prep(const float* __restrict__ coords, const float* __restrict__ box,
                       double* __restrict__ ws, int N) {
    int n = blockIdx.x * blockDim.x + threadIdx.x;
    if (n >= N) return;
    double bx[3][3], bi[3][3];
    load_box(box, bx, bi);

    int m = n % 3, o = (n / 3) * 3;
    int zat = (m == 0) ? n + 1 : o;
    int xat = (m == 0) ? n + 2 : ((m == 1) ? n + 1 : n - 1);
    d3 cn = getc(coords, n);
    d3 uz = normd(pbc(getc(coords, zat) - cn, bx, bi));
    d3 ux = normd(pbc(getc(coords, xat) - cn, bx, bi));
    d3 zax = (m == 0) ? normd(uz + ux) : uz;
    d3 xax = normd(ux - zax * dotd(ux, zax));
    d3 yax = crossd(zax, xax);
    // R columns = [xax yax zax]; R[a][k]
    double R[3][3] = {{xax.x, yax.x, zax.x},
                      {xax.y, yax.y, zax.y},
                      {xax.z, yax.z, zax.z}};
    int t = (m == 0) ? 0 : 1;

    double* mu = WS_MU(ws, N) + 3 * n;
    for (int a = 0; a < 3; ++a)
        mu[a] = R[a][0] * DIPO_[t][0] + R[a][1] * DIPO_[t][1] + R[a][2] * DIPO_[t][2];

    double q20 = QS_[t][0], q21c = QS_[t][1], q21s = QS_[t][2], q22c = QS_[t][3], q22s = QS_[t][4];
    double Ql[3][3] = {{-0.5 * q20 + SQ32 * q22c, SQ32 * q22s, SQ32 * q21c},
                       {SQ32 * q22s, -0.5 * q20 - SQ32 * q22c, SQ32 * q21s},
                       {SQ32 * q21c, SQ32 * q21s, q20}};
    double tmp[3][3];
    for (int a = 0; a < 3; ++a)
        for (int b = 0; b < 3; ++b)
            tmp[a][b] = R[a][0] * Ql[0][b] + R[a][1] * Ql[1][b] + R[a][2] * Ql[2][b];
    double* Qm = WS_QM(ws, N) + 9 * n;
    for (int a = 0; a < 3; ++a)
        for (int d = 0; d < 3; ++d)
            Qm[3 * a + d] = (tmp[a][0] * R[d][0] + tmp[a][1] * R[d][1] + tmp[a][2] * R[d][2]) / 3.0;

    double* al = WS_AL(ws, N) + 9 * n;
    for (int a = 0; a < 3; ++a)
        for (int d = 0; d < 3; ++d)
            al[3 * a + d] = R[a][0] * AD_[t][0] * R[d][0] + R[a][1] * AD_[t][1] * R[d][1] +
                            R[a][2] * AD_[t][2] * R[d][2];
}

__device__ inline double block_reduce(double v, double* sh) {
    int tid = threadIdx.x;
    sh[tid] = v;
    __syncthreads();
    for (int s = blockDim.x / 2; s > 0; s >>= 1) {
        if (tid < s) sh[tid] += sh[tid + s];
        __syncthreads();
    }
    double r = sh[0];
    __syncthreads();
    return r;
}

// -------------------- kernel 2: pair loop (block per atom) --------------------
__global__ void k_pairs(const float* __restrict__ coords, const float* __restrict__ box,
                        double* __restrict__ ws, int N) {
    int a = blockIdx.x;
    int tid = threadIdx.x;
    double bx[3][3], bi_[3][3];
    load_box(box, bx, bi_);

    int ta = (a % 3 == 0) ? 0 : 1;
    int wa = a / 3;
    d3 ca = getc(coords, a);
    const double* muA = WS_MU(ws, N) + 3 * a;
    const double* QA  = WS_QM(ws, N) + 9 * a;
    d3 mua = {muA[0], muA[1], muA[2]};
    double Qa[9];
    for (int k = 0; k < 9; ++k) Qa[k] = QA[k];

    double e = 0.0, dqa = 0.0;
    d3 Ef = {0.0, 0.0, 0.0};

    for (int b = tid; b < N; b += blockDim.x) {
        if (b / 3 == wa) continue;
        int tb = (b % 3 == 0) ? 0 : 1;
        d3 dr = pbc(getc(coords, b) - ca, bx, bi_);
        double r2 = dotd(dr, dr);
        if (r2 >= RCUT2) continue;
        double r = sqrt(r2);
        double inv_r = 1.0 / r;
        d3 nv = dr * inv_r;
        double r3 = r * r2;
        double inv_r2 = inv_r * inv_r;
        double inv_r3 = inv_r2 * inv_r;

        const double* muB = WS_MU(ws, N) + 3 * b;
        const double* QB  = WS_QM(ws, N) + 9 * b;
        d3 mub = {muB[0], muB[1], muB[2]};

        double muin = dotd(mua, nv), mujn = dotd(mub, nv);
        double nQni = nv.x * (Qa[0] * nv.x + Qa[1] * nv.y + Qa[2] * nv.z) +
                      nv.y * (Qa[3] * nv.x + Qa[4] * nv.y + Qa[5] * nv.z) +
                      nv.z * (Qa[6] * nv.x + Qa[7] * nv.y + Qa[8] * nv.z);
        double nQnj = nv.x * (QB[0] * nv.x + QB[1] * nv.y + QB[2] * nv.z) +
                      nv.y * (QB[3] * nv.x + QB[4] * nv.y + QB[5] * nv.z) +
                      nv.z * (QB[6] * nv.x + QB[7] * nv.y + QB[8] * nv.z);

        // ---- permanent electrostatics ----
        double bie = B_EL_[ta], bje = B_EL_[tb];
        double fd = f1damp(sqrt(bie * bje) * r);
        double qi = QSH_[ta], qj = QSH_[tb], Zi = Zc_[ta], Zj = Zc_[tb];
        double qti = Zi + qi, qtj = Zj + qj;
        double e_qq = (Zi * Zj + Zi * qj * f1damp(bje * r) + Zj * qi * f1damp(bie * r) +
                       qi * qj * fd) * inv_r;
        double e_qd = fd * (qtj * muin - qti * mujn) * inv_r2;
        double e_dd = fd * (dotd(mua, mub) - 3.0 * muin * mujn) * inv_r3;
        double e_qQ = 3.0 * fd * (qti * nQnj + qtj * nQni) * inv_r3;
        e += 0.5 * (e_qq + e_qd + e_dd + e_qQ);

        // ---- field for polarization (at atom a) ----
        double cq = -qtj * inv_r2;
        Ef.x += fd * (cq * nv.x + (3.0 * mujn * nv.x - mub.x) * inv_r3);
        Ef.y += fd * (cq * nv.y + (3.0 * mujn * nv.y - mub.y) * inv_r3);
        Ef.z += fd * (cq * nv.z + (3.0 * mujn * nv.z - mub.z) * inv_r3);

        // ---- charge transfer ----
        double qacc_a = QSH_[ta] * KM_AC_[ta], qacc_b = QSH_[tb] * KM_AC_[tb];
        double sdon_i = QSH_[ta] * KM_DO_[ta] + KD_DO_[ta] * muin + KQ_DO_[ta] * nQni;
        double sdon_j = QSH_[tb] * KM_DO_[tb] - KD_DO_[tb] * mujn + KQ_DO_[tb] * nQnj;
        double Sct = exp(-sqrt(B_CT_[ta] * B_CT_[tb]) * r);
        e += -0.5 * (sdon_i * qacc_b + sdon_j * qacc_a) * Sct * inv_r;
        double eps = (ta == tb) ? EPS_ON : EPS_OFF;
        dqa += sdon_j * qacc_a * Sct / (eps * r);

        // ---- Pauli repulsion ----
        double si_p = QSH_[ta] * KM_PA_[ta] + KD_PA_[ta] * muin + KQ_PA_[ta] * nQni;
        double sj_p = QSH_[tb] * KM_PA_[tb] - KD_PA_[tb] * mujn + KQ_PA_[tb] * nQnj;
        e += 0.5 * si_p * sj_p * exp(-sqrt(B_PA_[ta] * B_PA_[tb]) * r) * inv_r;

        // ---- exchange polarization (dipole/quad coeffs are zero) ----
        double si_x = QSH_[ta] * KM_XP_[ta], sj_x = QSH_[tb] * KM_XP_[tb];
        e += -0.5 * si_x * sj_x * exp(-sqrt(B_XP_[ta] * B_XP_[tb]) * r) * inv_r;

        // ---- Tang-Toennies dispersion ----
        double u = sqrt(B_D_[ta] * B_D_[tb]) * r;
        double poly = 1.0 + u * (1.0 + u * (1.0 / 2.0 + u * (1.0 / 6.0 + u * (1.0 / 24.0 +
                      u * (1.0 / 120.0 + u * (1.0 / 720.0))))));
        double f6 = 1.0 - exp(-u) * poly;
        e += -0.5 * f6 * sqrt(C6_[ta] * C6_[tb]) * inv_r3 * inv_r3;
    }

    __shared__ double sh[256];
    double etot = block_reduce(e, sh);
    double ex = block_reduce(Ef.x, sh);
    double ey = block_reduce(Ef.y, sh);
    double ez = block_reduce(Ef.z, sh);
    double dqt = block_reduce(dqa, sh);
    if (tid == 0) {
        double* EF = WS_EF(ws, N) + 3 * a;
        EF[0] = ex; EF[1] = ey; EF[2] = ez;
        WS_DQ(ws, N)[a] = dqt;
        WS_EP(ws, N)[a] = etot;
    }
}

// -------------------- kernel 3: finish (pol + ct_ind + bonded + reduce) ----------
__global__ void k_finish(const float* __restrict__ coords, const float* __restrict__ box,
                         const double* __restrict__ ws, float* __restrict__ out, int N) {
    int tid = threadIdx.x;
    int W = N / 3;
    double bx[3][3], bi_[3][3];
    load_box(box, bx, bi_);

    const double* AL = WS_AL((double*)ws, N);
    const double* EF = WS_EF((double*)ws, N);
    const double* DQ = WS_DQ((double*)ws, N);
    const double* EP = WS_EP((double*)ws, N);

    double e = 0.0;
    for (int i = tid; i < N; i += blockDim.x) {
        const double* A = AL + 9 * i;
        double E0 = EF[3 * i], E1 = EF[3 * i + 1], E2 = EF[3 * i + 2];
        double m0 = A[0] * E0 + A[1] * E1 + A[2] * E2;
        double m1 = A[3] * E0 + A[4] * E1 + A[5] * E2;
        double m2 = A[6] * E0 + A[7] * E1 + A[8] * E2;
        e += -0.5 * (m0 * E0 + m1 * E1 + m2 * E2);     // polarization
        int t = (i % 3 == 0) ? 0 : 1;
        e += 0.5 * ETA_[t] * DQ[i] * DQ[i];            // indirect CT
        e += EP[i];                                    // pair partials
    }

    double beta = sqrt(K_B / (2.0 * D_M));
    double cte = cos(TH_EQ);
    for (int w = tid; w < W; w += blockDim.x) {
        d3 cO = getc(coords, 3 * w);
        d3 b1 = pbc(getc(coords, 3 * w + 1) - cO, bx, bi_);
        d3 b2 = pbc(getc(coords, 3 * w + 2) - cO, bx, bi_);
        double l1 = sqrt(dotd(b1, b1)), l2 = sqrt(dotd(b2, b2));
        double x1 = 1.0 - exp(-beta * (l1 - B_EQ));
        double x2 = 1.0 - exp(-beta * (l2 - B_EQ));
        e += D_M * (x1 * x1 + x2 * x2);                        // Morse bonds
        e += K_BB * (l1 - B_EQ) * (l2 - B_EQ);                 // bond-bond
        double ca = dotd(b1, b2) / (l1 * l2);
        ca = fmin(fmax(ca, -1.0 + 1e-7), 1.0 - 1e-7);
        double th = acos(ca);
        e += 0.5 * K_TH * (ca - cte) * (ca - cte);             // angle
        e += K_BA * ((l1 - B_EQ) + (l2 - B_EQ)) * (th - TH_EQ);// bond-angle
    }

    __shared__ double sh[256];
    double tot = block_reduce(e, sh);
    if (tid == 0) out[0] = (float)tot;
}

extern "C" void kernel_launch(void* const* d_in, const int* in_sizes, int n_in,
                              void* d_out, int out_size, void* d_ws, size_t ws_size,
                              hipStream_t stream) {
    const float* coords = (const float*)d_in[0];
    const float* box    = (const float*)d_in[1];
    int N = in_sizes[0] / 3;  // 3W atoms
    double* ws = (double*)d_ws;
    float* out = (float*)d_out;

    k_prep<<<(N + 255) / 256, 256, 0, stream>>>(coords, box, ws, N);
    k_pairs<<<N, 256, 0, stream>>>(coords, box, ws, N);
    k_finish<<<1, 256, 0, stream>>>(coords, box, ws, out, N);
}

// Round 2
// 24.582 us; speedup vs baseline: 1.3772x; 1.3772x over previous
//
#include <hip/hip_runtime.h>
#include <math.h>

// ---------------- constants (atomic units) ----------------
constexpr double B2A   = 0.52917721067;
constexpr double H2KJ  = 2625.499638;
constexpr double RCUT  = 10.0 / B2A;
constexpr float  RCUT2F = (float)((10.0 / B2A) * (10.0 / B2A));

constexpr double Zc_[2]   = {3.61565, 0.93619};
constexpr double MONO_[2] = {-0.390896, 0.195448};
constexpr double QSH_[2]  = {MONO_[0] - Zc_[0], MONO_[1] - Zc_[1]};
constexpr double DIPO_[2][3] = {{0.0, 0.0, -0.094298},
                                {0.0910288, 0.0, -0.207851}};
constexpr double QS_[2][5] = {{-0.330685, 0.0, 0.0, 0.869923, 0.0},
                              {-0.0739388, 0.0929482, 0.0, 0.00532425, 0.0}};
constexpr double B_EL_[2]  = {2.13358, 2.33322};
constexpr double B_PA_[2]  = {2.1975, 1.96474};
constexpr double SPA_[2]   = {6.50923, 0.527804};      // qsh*(KM_PAULI/qsh)
constexpr double KD_PA_[2] = {-5.61925, -0.515584};
constexpr double KQ_PA_[2] = {-1.56567, -0.440164};
constexpr double C6_[2]    = {35.8289, 1.98954};
constexpr double B_D_[2]   = {1.84302, 1.30993};
constexpr double AD_[2][3] = {{4.45992, 6.07259, 4.55391},
                              {2.22001, 1.66835, 0.183855}};
constexpr double ETA_[2]   = {6.18699e-06 * 2.0, 0.561535 * 2.0};
constexpr double B_XP_[2]  = {2.73582, 2.04028};
constexpr double SXP_[2]   = {1.26592, 0.200089};
constexpr double B_CT_[2]  = {1.89485, 2.36763};
constexpr double SACC_[2]  = {-0.67857, 1.36735};
constexpr double SDON_[2]  = {0.757752, 0.00888982};
constexpr double KD_DO_[2] = {-0.512036, -0.0511668};
constexpr double KQ_DO_[2] = {-0.208186, 0.0568152};
constexpr double EPS_OFF = 0.380979;

constexpr double D_M   = 524.265 / H2KJ;
constexpr double K_B   = 5098.15 / H2KJ * B2A * B2A;
constexpr double B_EQ  = 0.958413 / B2A;
constexpr double K_BB  = -61.1423 / H2KJ * B2A * B2A;
constexpr double K_BA  = -159.886 / H2KJ * B2A;
constexpr double TH_EQ = 104.4234 * M_PI / 180.0;
constexpr double K_TH  = 452.183 / H2KJ;
constexpr double SQ32  = 0.86602540378443864676;

#define NCHUNK 2
#define TF(A, t) ((t) ? (float)A[1] : (float)A[0])
#define S(x) (tb ? x##1 : x##0)

// ---------------- f32 vec helpers ----------------
struct f3 { float x, y, z; };
__device__ inline f3 operator-(f3 a, f3 b) { return {a.x - b.x, a.y - b.y, a.z - b.z}; }
__device__ inline f3 operator+(f3 a, f3 b) { return {a.x + b.x, a.y + b.y, a.z + b.z}; }
__device__ inline f3 operator*(f3 a, float s) { return {a.x * s, a.y * s, a.z * s}; }
__device__ inline float dotf(f3 a, f3 b) { return a.x * b.x + a.y * b.y + a.z * b.z; }
__device__ inline f3 crossf(f3 a, f3 b) {
    return {a.y * b.z - a.z * b.y, a.z * b.x - a.x * b.z, a.x * b.y - a.y * b.x};
}
__device__ inline f3 normf(f3 a) { float s = rsqrtf(dotf(a, a)); return a * s; }
__device__ inline f3 getcf(const float* c, int i) {
    return {c[3 * i], c[3 * i + 1], c[3 * i + 2]};
}
__device__ inline void load_boxf(const float* box, float bx[3][3], float bi[3][3]) {
    for (int i = 0; i < 3; ++i)
        for (int j = 0; j < 3; ++j) bx[i][j] = box[i * 3 + j];
    float a = bx[0][0], b = bx[0][1], c = bx[0][2];
    float d = bx[1][0], e = bx[1][1], f = bx[1][2];
    float g = bx[2][0], h = bx[2][1], i2 = bx[2][2];
    float A =  (e * i2 - f * h), B = -(d * i2 - f * g), C =  (d * h - e * g);
    float D = -(b * i2 - c * h), E =  (a * i2 - c * g), F = -(a * h - b * g);
    float G =  (b * f - c * e),  H = -(a * f - c * d),  I =  (a * e - b * d);
    float s = 1.0f / (a * A + b * B + c * C);
    bi[0][0] = A * s; bi[0][1] = D * s; bi[0][2] = G * s;
    bi[1][0] = B * s; bi[1][1] = E * s; bi[1][2] = H * s;
    bi[2][0] = C * s; bi[2][1] = F * s; bi[2][2] = I * s;
}
__device__ inline f3 pbcf(f3 d, const float bx[3][3], const float bi[3][3]) {
    float s0 = rintf(d.x * bi[0][0] + d.y * bi[1][0] + d.z * bi[2][0]);
    float s1 = rintf(d.x * bi[0][1] + d.y * bi[1][1] + d.z * bi[2][1]);
    float s2 = rintf(d.x * bi[0][2] + d.y * bi[1][2] + d.z * bi[2][2]);
    d.x -= s0 * bx[0][0] + s1 * bx[1][0] + s2 * bx[2][0];
    d.y -= s0 * bx[0][1] + s1 * bx[1][1] + s2 * bx[2][1];
    d.z -= s0 * bx[0][2] + s1 * bx[1][2] + s2 * bx[2][2];
    return d;
}
__device__ inline float f1mf(float u) { return -__expf(-u) * (1.0f + 0.5f * u); }  // f1 - 1

// ---------------- f64 helpers (bonded terms) ----------------
struct d3 { double x, y, z; };
__device__ inline d3 subd(d3 a, d3 b) { return {a.x - b.x, a.y - b.y, a.z - b.z}; }
__device__ inline double dotd(d3 a, d3 b) { return a.x * b.x + a.y * b.y + a.z * b.z; }
__device__ inline d3 getcd(const float* c, int i) {
    return {(double)c[3 * i], (double)c[3 * i + 1], (double)c[3 * i + 2]};
}
__device__ inline void load_boxd(const float* box, double bx[3][3], double bi[3][3]) {
    for (int i = 0; i < 3; ++i)
        for (int j = 0; j < 3; ++j) bx[i][j] = (double)box[i * 3 + j];
    double a = bx[0][0], b = bx[0][1], c = bx[0][2];
    double d = bx[1][0], e = bx[1][1], f = bx[1][2];
    double g = bx[2][0], h = bx[2][1], i2 = bx[2][2];
    double A =  (e * i2 - f * h), B = -(d * i2 - f * g), C =  (d * h - e * g);
    double D = -(b * i2 - c * h), E =  (a * i2 - c * g), F = -(a * h - b * g);
    double G =  (b * f - c * e),  H = -(a * f - c * d),  I =  (a * e - b * d);
    double s = 1.0 / (a * A + b * B + c * C);
    bi[0][0] = A * s; bi[0][1] = D * s; bi[0][2] = G * s;
    bi[1][0] = B * s; bi[1][1] = E * s; bi[1][2] = H * s;
    bi[2][0] = C * s; bi[2][1] = F * s; bi[2][2] = I * s;
}
__device__ inline d3 pbcd(d3 d, const double bx[3][3], const double bi[3][3]) {
    double s0 = rint(d.x * bi[0][0] + d.y * bi[1][0] + d.z * bi[2][0]);
    double s1 = rint(d.x * bi[0][1] + d.y * bi[1][1] + d.z * bi[2][1]);
    double s2 = rint(d.x * bi[0][2] + d.y * bi[1][2] + d.z * bi[2][2]);
    d.x -= s0 * bx[0][0] + s1 * bx[1][0] + s2 * bx[2][0];
    d.y -= s0 * bx[0][1] + s1 * bx[1][1] + s2 * bx[2][1];
    d.z -= s0 * bx[0][2] + s1 * bx[1][2] + s2 * bx[2][2];
    return d;
}

// ---------------- shared frame computation (f32) ----------------
__device__ inline void calc_frame(const float* coords, const float bx[3][3],
                                  const float bi[3][3], int n, float R[3][3], int* tt) {
    int w = n / 3, m = n - w * 3, o = w * 3;
    int zat = (m == 0) ? n + 1 : o;
    int xat = (m == 0) ? n + 2 : ((m == 1) ? n + 1 : n - 1);
    f3 cn = getcf(coords, n);
    f3 uz = normf(pbcf(getcf(coords, zat) - cn, bx, bi));
    f3 ux = normf(pbcf(getcf(coords, xat) - cn, bx, bi));
    f3 zax = (m == 0) ? normf(uz + ux) : uz;
    f3 xax = normf(ux - zax * dotf(ux, zax));
    f3 yax = crossf(zax, xax);
    R[0][0] = xax.x; R[0][1] = yax.x; R[0][2] = zax.x;
    R[1][0] = xax.y; R[1][1] = yax.y; R[1][2] = zax.y;
    R[2][0] = xax.z; R[2][1] = yax.z; R[2][2] = zax.z;
    *tt = (m == 0) ? 0 : 1;
}

// ws layout: floats [mu 3N | Qm6 6N] then (8-aligned) doubles [EP 2N | EF 6N | DQ 2N]
__device__ inline double* wsd_from(float* wsf, int N) {
    return (double*)(wsf + 9 * ((size_t)N));  // 9N*4 bytes, divisible by 8 when N even
}

// -------------------- kernel 1: mu + Qm (f32) --------------------
__global__ void k_prep(const float* __restrict__ coords, const float* __restrict__ box,
                       float* __restrict__ wsf, int N) {
    int n = blockIdx.x * blockDim.x + threadIdx.x;
    if (n >= N) return;
    float bx[3][3], bi[3][3];
    load_boxf(box, bx, bi);
    float R[3][3]; int t;
    calc_frame(coords, bx, bi, n, R, &t);

    float d0 = t ? (float)DIPO_[1][0] : (float)DIPO_[0][0];
    float d1 = t ? (float)DIPO_[1][1] : (float)DIPO_[0][1];
    float d2 = t ? (float)DIPO_[1][2] : (float)DIPO_[0][2];
    float* mu = wsf + 3 * n;
    mu[0] = R[0][0] * d0 + R[0][1] * d1 + R[0][2] * d2;
    mu[1] = R[1][0] * d0 + R[1][1] * d1 + R[1][2] * d2;
    mu[2] = R[2][0] * d0 + R[2][1] * d1 + R[2][2] * d2;

    float q20  = t ? (float)QS_[1][0] : (float)QS_[0][0];
    float q21c = t ? (float)QS_[1][1] : (float)QS_[0][1];
    float q21s = t ? (float)QS_[1][2] : (float)QS_[0][2];
    float q22c = t ? (float)QS_[1][3] : (float)QS_[0][3];
    float q22s = t ? (float)QS_[1][4] : (float)QS_[0][4];
    const float s32 = (float)SQ32;
    float Ql[3][3] = {{-0.5f * q20 + s32 * q22c, s32 * q22s, s32 * q21c},
                      {s32 * q22s, -0.5f * q20 - s32 * q22c, s32 * q21s},
                      {s32 * q21c, s32 * q21s, q20}};
    float tmp[3][3];
    for (int a = 0; a < 3; ++a)
        for (int b = 0; b < 3; ++b)
            tmp[a][b] = R[a][0] * Ql[0][b] + R[a][1] * Ql[1][b] + R[a][2] * Ql[2][b];
    float G[3][3];
    for (int a = 0; a < 3; ++a)
        for (int d = 0; d < 3; ++d)
            G[a][d] = (tmp[a][0] * R[d][0] + tmp[a][1] * R[d][1] + tmp[a][2] * R[d][2]) *
                      (1.0f / 3.0f);
    float* Q = wsf + 3 * N + 6 * n;
    Q[0] = G[0][0]; Q[1] = G[0][1]; Q[2] = G[0][2];
    Q[3] = G[1][1]; Q[4] = G[1][2]; Q[5] = G[2][2];
}

__device__ inline double wred(double v) {
    for (int off = 32; off > 0; off >>= 1) v += __shfl_xor(v, off);
    return v;
}

// -------------------- kernel 2: pair loop (wave per atom-chunk, f32 math) ---------
__global__ void __launch_bounds__(64) k_pairs(const float* __restrict__ coords,
                                              const float* __restrict__ box,
                                              float* __restrict__ wsf, int N) {
    int bid = blockIdx.x;
    int a = bid >> 1;        // NCHUNK = 2
    int chunk = bid & 1;
    int lane = threadIdx.x;
    float bx[3][3], bi[3][3];
    load_boxf(box, bx, bi);

    int wa = a / 3;
    int ta = (a - wa * 3) ? 1 : 0;
    f3 ca = getcf(coords, a);
    const float* muA = wsf + 3 * a;
    f3 mua = {muA[0], muA[1], muA[2]};
    const float* QA = wsf + 3 * N + 6 * a;
    float Qaxx = QA[0], Qaxy = QA[1], Qaxz = QA[2], Qayy = QA[3], Qayz = QA[4], Qazz = QA[5];

    // per-atom / type-pair constants (tb-dual registers)
    float Zi = TF(Zc_, ta), qi = TF(QSH_, ta), qti = Zi + qi;
    float beli = TF(B_EL_, ta);
    float belj0 = (float)B_EL_[0], belj1 = (float)B_EL_[1];
    float bije0 = sqrtf(beli * belj0), bije1 = sqrtf(beli * belj1);
    float qtj0 = (float)(Zc_[0] + QSH_[0]), qtj1 = (float)(Zc_[1] + QSH_[1]);
    float Ziqj0 = Zi * (float)QSH_[0], Ziqj1 = Zi * (float)QSH_[1];
    float Zjqi0 = (float)Zc_[0] * qi, Zjqi1 = (float)Zc_[1] * qi;
    float qiqj0 = qi * (float)QSH_[0], qiqj1 = qi * (float)QSH_[1];
    float qq0 = qti * qtj0, qq1 = qti * qtj1;
    float sacci = TF(SACC_, ta);
    float saccj0 = (float)SACC_[0], saccj1 = (float)SACC_[1];
    float sdi = TF(SDON_, ta), kddi = TF(KD_DO_, ta), kqdi = TF(KQ_DO_, ta);
    float sdj0 = (float)SDON_[0], sdj1 = (float)SDON_[1];
    float kddj0 = (float)KD_DO_[0], kddj1 = (float)KD_DO_[1];
    float kqdj0 = (float)KQ_DO_[0], kqdj1 = (float)KQ_DO_[1];
    float bctt = TF(B_CT_, ta);
    float bijct0 = sqrtf(bctt * (float)B_CT_[0]), bijct1 = sqrtf(bctt * (float)B_CT_[1]);
    float inve0 = (ta == 0) ? 1e-15f : (float)(1.0 / EPS_OFF);
    float inve1 = (ta == 1) ? 1e-15f : (float)(1.0 / EPS_OFF);
    float spi = TF(SPA_, ta), kdpi = TF(KD_PA_, ta), kqpi = TF(KQ_PA_, ta);
    float spj0 = (float)SPA_[0], spj1 = (float)SPA_[1];
    float kdpj0 = (float)KD_PA_[0], kdpj1 = (float)KD_PA_[1];
    float kqpj0 = (float)KQ_PA_[0], kqpj1 = (float)KQ_PA_[1];
    float bpat = TF(B_PA_, ta);
    float bijpa0 = sqrtf(bpat * (float)B_PA_[0]), bijpa1 = sqrtf(bpat * (float)B_PA_[1]);
    float bxpt = TF(B_XP_, ta);
    float bijxp0 = sqrtf(bxpt * (float)B_XP_[0]), bijxp1 = sqrtf(bxpt * (float)B_XP_[1]);
    float sxpi = TF(SXP_, ta);
    float cxp0 = sxpi * (float)SXP_[0], cxp1 = sxpi * (float)SXP_[1];
    float bdt = TF(B_D_, ta);
    float bijd0 = sqrtf(bdt * (float)B_D_[0]), bijd1 = sqrtf(bdt * (float)B_D_[1]);
    float c6t = TF(C6_, ta);
    float c60 = sqrtf(c6t * (float)C6_[0]), c61 = sqrtf(c6t * (float)C6_[1]);

    double e = 0.0, efx = 0.0, efy = 0.0, efz = 0.0, dqa = 0.0;
    int iters = (N + 64 * NCHUNK - 1) / (64 * NCHUNK);
    int b0 = chunk * iters * 64 + lane;
    for (int k = 0; k < iters; ++k) {
        int b = b0 + k * 64;
        if (b >= N) break;
        int wb = b / 3;
        if (wb == wa) continue;
        f3 dr = pbcf(getcf(coords, b) - ca, bx, bi);
        float r2 = dotf(dr, dr);
        if (r2 >= RCUT2F) continue;
        int tb = (b - wb * 3) ? 1 : 0;
        float invr = rsqrtf(r2);
        float r = r2 * invr;
        f3 nv = dr * invr;
        float invr2 = invr * invr, invr3 = invr2 * invr;
        const float* muB = wsf + 3 * b;
        f3 mub = {muB[0], muB[1], muB[2]};
        const float* QB = wsf + 3 * N + 6 * b;
        float muin = dotf(mua, nv), mujn = dotf(mub, nv);
        float nQni = Qaxx * nv.x * nv.x + Qayy * nv.y * nv.y + Qazz * nv.z * nv.z +
                     2.f * (Qaxy * nv.x * nv.y + Qaxz * nv.x * nv.z + Qayz * nv.y * nv.z);
        float nQnj = QB[0] * nv.x * nv.x + QB[3] * nv.y * nv.y + QB[5] * nv.z * nv.z +
                     2.f * (QB[1] * nv.x * nv.y + QB[2] * nv.x * nv.z + QB[4] * nv.y * nv.z);

        // permanent electrostatics (e_qq rearranged: no large-term cancellation)
        float fdm = f1mf(S(bije) * r);
        float fd = 1.f + fdm;
        float ep = (S(qq) + S(Ziqj) * f1mf(S(belj) * r) + S(Zjqi) * f1mf(beli * r) +
                    S(qiqj) * fdm) * invr;
        ep += fd * (S(qtj) * muin - qti * mujn) * invr2;
        ep += fd * (dotf(mua, mub) - 3.f * muin * mujn) * invr3;
        ep += 3.f * fd * (qti * nQnj + S(qtj) * nQni) * invr3;

        // field at atom a
        float cc = -S(qtj) * invr2 + 3.f * mujn * invr3;
        efx += (double)(fd * (cc * nv.x - mub.x * invr3));
        efy += (double)(fd * (cc * nv.y - mub.y * invr3));
        efz += (double)(fd * (cc * nv.z - mub.z * invr3));

        // charge transfer
        float sdon_i = sdi + kddi * muin + kqdi * nQni;
        float sdon_j = S(sdj) - S(kddj) * mujn + S(kqdj) * nQnj;
        float sct_r = __expf(-S(bijct) * r) * invr;
        ep -= (sdon_i * S(saccj) + sdon_j * sacci) * sct_r;
        dqa += (double)(sdon_j * sacci * sct_r * S(inve));

        // Pauli repulsion
        float si = spi + kdpi * muin + kqpi * nQni;
        float sj = S(spj) - S(kdpj) * mujn + S(kqpj) * nQnj;
        ep += si * sj * __expf(-S(bijpa) * r) * invr;

        // exchange polarization
        ep -= S(cxp) * __expf(-S(bijxp) * r) * invr;

        // Tang-Toennies dispersion
        float u = S(bijd) * r;
        float poly = 1.f + u * (1.f + u * (0.5f + u * (0.16666667f + u * (4.1666667e-2f +
                     u * (8.3333333e-3f + u * 1.3888889e-3f)))));
        ep -= (1.f - __expf(-u) * poly) * S(c6) * invr3 * invr3;

        e += (double)ep;
    }

    e = wred(e); efx = wred(efx); efy = wred(efy); efz = wred(efz); dqa = wred(dqa);
    if (lane == 0) {
        double* wsd = wsd_from(wsf, N);
        wsd[chunk * N + a] = 0.5 * e;                       // EP
        double* EF = wsd + 2 * N + (chunk * N + a) * 3;     // EF
        EF[0] = efx; EF[1] = efy; EF[2] = efz;
        wsd[8 * N + chunk * N + a] = dqa;                   // DQ
    }
}

// -------------------- kernel 3: polarization + CT-ind + bonded + reduce ----------
__global__ void k_finish(const float* __restrict__ coords, const float* __restrict__ box,
                         float* __restrict__ wsf, float* __restrict__ out, int N) {
    int tid = threadIdx.x;
    int W = N / 3;
    float bx[3][3], bi[3][3];
    load_boxf(box, bx, bi);
    double bxd[3][3], bid[3][3];
    load_boxd(box, bxd, bid);
    const double* wsd = wsd_from(wsf, N);

    double e = 0.0;
    for (int i = tid; i < N; i += blockDim.x) {
        float R[3][3]; int t;
        calc_frame(coords, bx, bi, i, R, &t);
        float a0 = t ? (float)AD_[1][0] : (float)AD_[0][0];
        float a1 = t ? (float)AD_[1][1] : (float)AD_[0][1];
        float a2 = t ? (float)AD_[1][2] : (float)AD_[0][2];
        double al[3][3];
        for (int p = 0; p < 3; ++p)
            for (int q = 0; q < 3; ++q)
                al[p][q] = (double)(R[p][0] * a0 * R[q][0] + R[p][1] * a1 * R[q][1] +
                                    R[p][2] * a2 * R[q][2]);
        const double* EF = wsd + 2 * N;
        double E0 = EF[i * 3 + 0] + EF[(N + i) * 3 + 0];
        double E1 = EF[i * 3 + 1] + EF[(N + i) * 3 + 1];
        double E2 = EF[i * 3 + 2] + EF[(N + i) * 3 + 2];
        double m0 = al[0][0] * E0 + al[0][1] * E1 + al[0][2] * E2;
        double m1 = al[1][0] * E0 + al[1][1] * E1 + al[1][2] * E2;
        double m2 = al[2][0] * E0 + al[2][1] * E1 + al[2][2] * E2;
        e += -0.5 * (m0 * E0 + m1 * E1 + m2 * E2);              // polarization
        double dq = wsd[8 * N + i] + wsd[8 * N + N + i];
        e += 0.5 * (t ? ETA_[1] : ETA_[0]) * dq * dq;           // indirect CT
        e += wsd[i] + wsd[N + i];                               // pair partials
    }

    double beta = sqrt(K_B / (2.0 * D_M));
    double cte = cos(TH_EQ);
    for (int w = tid; w < W; w += blockDim.x) {
        d3 cO = getcd(coords, 3 * w);
        d3 b1 = pbcd(subd(getcd(coords, 3 * w + 1), cO), bxd, bid);
        d3 b2 = pbcd(subd(getcd(coords, 3 * w + 2), cO), bxd, bid);
        double l1 = sqrt(dotd(b1, b1)), l2 = sqrt(dotd(b2, b2));
        double x1 = 1.0 - exp(-beta * (l1 - B_EQ));
        double x2 = 1.0 - exp(-beta * (l2 - B_EQ));
        e += D_M * (x1 * x1 + x2 * x2);
        e += K_BB * (l1 - B_EQ) * (l2 - B_EQ);
        double ca = dotd(b1, b2) / (l1 * l2);
        ca = fmin(fmax(ca, -1.0 + 1e-7), 1.0 - 1e-7);
        double th = acos(ca);
        e += 0.5 * K_TH * (ca - cte) * (ca - cte);
        e += K_BA * ((l1 - B_EQ) + (l2 - B_EQ)) * (th - TH_EQ);
    }

    __shared__ double sh[256];
    sh[tid] = e;
    __syncthreads();
    for (int s = blockDim.x / 2; s > 0; s >>= 1) {
        if (tid < s) sh[tid] += sh[tid + s];
        __syncthreads();
    }
    if (tid == 0) out[0] = (float)sh[0];
}

extern "C" void kernel_launch(void* const* d_in, const int* in_sizes, int n_in,
                              void* d_out, int out_size, void* d_ws, size_t ws_size,
                              hipStream_t stream) {
    const float* coords = (const float*)d_in[0];
    const float* box    = (const float*)d_in[1];
    int N = in_sizes[0] / 3;  // atoms
    float* wsf = (float*)d_ws;
    float* out = (float*)d_out;

    k_prep<<<(N + 255) / 256, 256, 0, stream>>>(coords, box, wsf, N);
    k_pairs<<<N * NCHUNK, 64, 0, stream>>>(coords, box, wsf, N);
    k_finish<<<1, 256, 0, stream>>>(coords, box, wsf, out, N);
}